// Round 6
// baseline (1568.055 us; speedup 1.0000x reference)
//
#include <hip/hip_runtime.h>
#include <math.h>

#define S 128
#define L 16384
#define AK 25
#define KA 625
#define LK 49
#define KL 2401
#define XW 152
#define PI2 1.57079632679489662f
#define MSCALE 1024.0f
#define NBLK 512
#define JROW 52           // padded weight-row width (49 -> 52)
#define WINW 84           // smoothed window cols
#define WINSZ 4160        // 49*84 = 4116 padded to 4160 (PROW*4)
#define PROW 1040
#define RAWW 88
#define RAWSZ 4664        // 53*88

typedef float v4f __attribute__((ext_vector_type(4)));
typedef _Float16 v4h __attribute__((ext_vector_type(4)));

// ws float offsets
#define WS_AENVD   0        // deinterleaved aff env (628)
#define WS_SRE     1024     // 25
#define WS_LRIRAW  2048     // 2401 scratch
#define WS_LRIJ    5120     // 2560, j-layout lri
#define WS_AFF     8192     // 16384
#define WS_CTR     24576    // 16 uint barrier counters
#define WS_BUF0    40960    // lat ping
#define WS_BUF1    57344    // lat pong
#define WS_LMB     73728    // lat_mean exchange

// out float offsets: raw_aff[16384], lat[16384], corr[1], x_tiles[10240000]
#define OUT_LAT   16384
#define OUT_CORR  32768
#define OUT_XT    32769

__global__ __launch_bounds__(256) void init_consts(float* __restrict__ ws) {
    const int t = threadIdx.x;
    float* aenvd  = ws + WS_AENVD;
    float* sre    = ws + WS_SRE;
    float* lrraw  = ws + WS_LRIRAW;
    float* lriJ   = ws + WS_LRIJ;
    unsigned* ctr = (unsigned*)(ws + WS_CTR);
    __shared__ float red[256];

    if (t < 16) ctr[t] = 0u;

    for (int k = t; k < KA; k += 256) {
        int ky = k / AK, kx = k - ky * AK;
        float dy = (float)ky - 12.0f, dx = (float)kx - 12.0f;
        float rd = sqrtf(dx*dx + dy*dy);
        float c  = cosf(fminf(rd * (1.0f/25.0f), 1.0f) * PI2);
        aenvd[(k & 3) * 157 + (k >> 2)] = c*c * (rd < 12.5f ? 1.0f : 0.0f);
    }

    float myv = 0.0f;
    if (t < 25) {
        int ky = t / 5, kx = t - ky * 5;
        float dy = (float)ky - 2.0f, dx = (float)kx - 2.0f;
        float rd = sqrtf(dx*dx + dy*dy);
        float c  = cosf(fminf(rd * 0.2f, 1.0f) * PI2);
        myv = c*c * (rd < 2.5f ? 1.0f : 0.0f);
    }
    red[t] = myv;
    __syncthreads();
    for (int off = 128; off > 0; off >>= 1) {
        if (t < off) red[t] += red[t + off];
        __syncthreads();
    }
    float ssum = red[0];
    __syncthreads();
    if (t < 25) sre[t] = myv / ssum;

    float localmax = 0.0f;
    for (int k = t; k < KL; k += 256) {
        int ky = k / LK, kx = k - ky * LK;
        float dy = (float)ky - 24.0f, dx = (float)kx - 24.0f;
        float rd = sqrtf(dx*dx + dy*dy);
        float ci = cosf(fminf(rd * 0.2f, 1.0f) * PI2);
        float im = ci*ci * (rd < 2.5f ? 1.0f : 0.0f);
        float co = cosf(fminf(rd * (1.0f/49.0f), 1.0f) * PI2);
        float le = co*co * (rd < 24.5f ? 1.0f : 0.0f) * (1.0f - im);
        lrraw[k] = le;
        localmax = fmaxf(localmax, le);
    }
    red[t] = localmax;
    __syncthreads();
    for (int off = 128; off > 0; off >>= 1) {
        if (t < off) red[t] = fmaxf(red[t], red[t + off]);
        __syncthreads();
    }
    float invm = 1.0f / red[0];
    __syncthreads();
    // j-layout lri: j in [0,2560), row width 52, cols 49..51 and j>=2548 are 0
    for (int j = t; j < 2560; j += 256) {
        int ky = j / JROW, kx = j - ky * JROW;
        float v = 0.0f;
        if (j < 2548 && kx < 49) v = lrraw[ky * 49 + kx] * invm;
        lriJ[j] = v;
    }
}

// Afferent (unchanged from R5, passing)
__global__ __launch_bounds__(256) void aff_kernel(
    const float* __restrict__ x, const float* __restrict__ rfs,
    const float* __restrict__ ada, const float* __restrict__ aenv_d,
    float* __restrict__ raw_aff_out, float* __restrict__ xtiles_out,
    float* __restrict__ aff_ws)
{
    __shared__ float xwin[700];
    __shared__ float env[628];
    const int tid = threadIdx.x;
    const int wave = tid >> 6, lane = tid & 63;
    const int unit0 = blockIdx.x * 4;
    const int r0 = unit0 >> 7, c0 = unit0 & 127;

    for (int i = tid; i < 628; i += 256) env[i] = aenv_d[i];
    for (int i = tid; i < 700; i += 256) {
        int wy = i / 28, wx = i - wy * 28;
        xwin[(i & 3) * 175 + (i >> 2)] = x[(r0 + wy) * XW + c0 + wx];
    }
    __syncthreads();

    const int unit = unit0 + wave;
    const int base = unit * KA;
    const int h = (-base) & 3;
    const int tl = (base + KA) & 3;
    const int m4 = (KA - h - tl) >> 2;
    const int rem = m4 - 128;

    const v4f* w4p = (const v4f*)(rfs + base + h);
    v4f wv0 = w4p[lane];
    v4f wv1 = w4p[lane + 64];
    v4f wv2 = (v4f)(0.0f);
    bool has2 = lane < rem;
    if (has2) wv2 = w4p[128 + lane];
    float wh = 0.0f, wt = 0.0f;
    if (lane < h)  wh = rfs[base + lane];
    if (lane < tl) wt = rfs[base + KA - tl + lane];

    float* trow = xtiles_out + (size_t)unit * KA;
    v4f* t4p = (v4f*)(trow + h);
    float adot = 0.0f, rsum = 0.0f;

    if (lane < h) {
        int j = lane + wave;
        float xt = xwin[(j & 3) * 175 + (j >> 2)] * env[(lane & 3) * 157 + (lane >> 2)];
        trow[lane] = xt;
        adot = fmaf(xt, wh, adot); rsum += wh;
    }
    if (lane < tl) {
        int k = KA - tl + lane;
        int ky = (int)(((unsigned)k * 83887u) >> 21);
        int j = k + 3 * ky + wave;
        float xt = xwin[(j & 3) * 175 + (j >> 2)] * env[(k & 3) * 157 + (k >> 2)];
        trow[k] = xt;
        adot = fmaf(xt, wt, adot); rsum += wt;
    }
    #pragma unroll
    for (int i = 0; i < 2; i++) {
        v4f wq = (i == 0) ? wv0 : wv1;
        int q = lane + (i << 6);
        int kq = h + (q << 2);
        v4f st;
        #pragma unroll
        for (int e = 0; e < 4; e++) {
            int k = kq + e;
            int ky = (int)(((unsigned)k * 83887u) >> 21);
            int j = k + 3 * ky + wave;
            float xt = xwin[(j & 3) * 175 + (j >> 2)] * env[(k & 3) * 157 + (k >> 2)];
            st[e] = xt;
            adot = fmaf(xt, wq[e], adot);
            rsum += wq[e];
        }
        __builtin_nontemporal_store(st, &t4p[q]);
    }
    if (has2) {
        int q = 128 + lane;
        int kq = h + (q << 2);
        v4f st;
        #pragma unroll
        for (int e = 0; e < 4; e++) {
            int k = kq + e;
            int ky = (int)(((unsigned)k * 83887u) >> 21);
            int j = k + 3 * ky + wave;
            float xt = xwin[(j & 3) * 175 + (j >> 2)] * env[(k & 3) * 157 + (k >> 2)];
            st[e] = xt;
            adot = fmaf(xt, wv2[e], adot);
            rsum += wv2[e];
        }
        __builtin_nontemporal_store(st, &t4p[q]);
    }

    for (int off = 32; off > 0; off >>= 1) {
        adot += __shfl_down(adot, off);
        rsum += __shfl_down(rsum, off);
    }
    if (lane == 0) {
        float inv = 1.0f / rsum;
        raw_aff_out[unit] = 62.5f * adot * inv;
        aff_ws[unit] = adot * inv - ada[unit];
    }
}

__device__ __forceinline__ void gbar(unsigned* ctr, int idx) {
    __syncthreads();
    if (threadIdx.x == 0) {
        __hip_atomic_fetch_add(&ctr[idx], 1u, __ATOMIC_ACQ_REL, __HIP_MEMORY_SCOPE_AGENT);
        long guard = 0;
        while (__hip_atomic_load(&ctr[idx], __ATOMIC_ACQUIRE, __HIP_MEMORY_SCOPE_AGENT) < (unsigned)NBLK) {
            __builtin_amdgcn_s_sleep(8);
            if (++guard > 100000000L) break;   // fail visibly, never hang
        }
    }
    __syncthreads();
}

// Persistent fused kernel: weights live in registers (8 units/wave x 2560 halves).
// 512 blocks x 256 threads, 2 blocks/CU co-resident.
__global__ __launch_bounds__(256, 2) void fused_kernel(
    const float* __restrict__ lw, const float* __restrict__ lriJ,
    const float* __restrict__ sre_g, const float* __restrict__ aff_ws,
    const float* __restrict__ last_lat, const float* __restrict__ lm0,
    float* __restrict__ buf0, float* __restrict__ buf1,
    float* __restrict__ lmb, unsigned* __restrict__ ctr,
    float* __restrict__ out_lat, float* __restrict__ out_corr)
{
    __shared__ float raw[RAWSZ];
    __shared__ float win[WINSZ];   // perm layout: p = (a&3)*PROW + (a>>2)
    __shared__ float bred[4];

    const int tid = threadIdx.x;
    const int wave = tid >> 6, lane = tid & 63;
    const int blk = blockIdx.x;
    const int r  = blk >> 2;
    const int c0 = (blk & 3) << 5;

    float sreR[25];
    #pragma unroll
    for (int i = 0; i < 25; i++) sreR[i] = sre_g[i];

    // zero pad region of win (read x0-weight; must be finite)
    for (int a = 4116 + tid; a < WINSZ; a += 256)
        win[(a & 3) * PROW + (a >> 2)] = 0.0f;
    if (blk == 0 && tid == 0)
        __hip_atomic_store(out_corr, 0.0f, __ATOMIC_RELAXED, __HIP_MEMORY_SCOPE_AGENT);

    // per-lane quad geometry: i-th quad -> j = 4*(lane+64i); boff = ky*84+kx
    int boff[10];
    #pragma unroll
    for (int i = 0; i < 10; i++) {
        int j = (lane + (i << 6)) << 2;
        int ky = (int)(((unsigned)j * 20165u) >> 20);
        boff[i] = ky * WINW + (j - ky * JROW);
    }

    // ---- Phase A: load weights once, convert to scaled fp16 in registers ----
    v4h W[8][10];
    float lm_r[8], aff_r[8];
    #pragma unroll
    for (int u = 0; u < 8; u++) {
        const int unit = r * S + c0 + (wave << 3) + u;
        const int base = unit * KL;
        const int h = (-base) & 3;
        const int tl = (base + KL) & 3;
        const int m4 = (KL - h - tl) >> 2;
        const int rem = m4 - 576;
        const v4f* w4p = (const v4f*)(lw + base + h);
        float wsum = 0.0f;
        #pragma unroll
        for (int i = 0; i < 9; i++) {
            v4f q = w4p[lane + (i << 6)];
            wsum += (q[0] + q[1]) + (q[2] + q[3]);
        }
        if (lane < rem) { v4f q = w4p[576 + lane]; wsum += (q[0] + q[1]) + (q[2] + q[3]); }
        if (lane < h)  wsum += lw[base + lane];
        if (lane < tl) wsum += lw[base + KL - tl + lane];
        #pragma unroll
        for (int off = 1; off < 64; off <<= 1) wsum += __shfl_xor(wsum, off);
        const float scale = MSCALE / wsum;

        #pragma unroll
        for (int i = 0; i < 10; i++) {
            int j0 = (lane + (i << 6)) << 2;
            int ky = (int)(((unsigned)j0 * 20165u) >> 20);
            int kx0 = j0 - ky * JROW;
            v4h wq;
            #pragma unroll
            for (int e = 0; e < 4; e++) {
                int kx = kx0 + e;
                float val = 0.0f;
                if (j0 + e < 2548 && kx < 49)
                    val = lw[base + ky * 49 + kx] * lriJ[j0 + e] * scale;
                wq[e] = (_Float16)val;
            }
            W[u][i] = wq;
        }
        aff_r[u] = aff_ws[unit];
        lm_r[u]  = lm0[unit];
    }

    // ---- Phase B: 10 lateral iterations ----
    float* bufs[2] = { buf0, buf1 };
    for (int it = 0; it < 10; ++it) {
        const float* src = (it == 0) ? last_lat : bufs[(it - 1) & 1];
        // stage raw lat window (reflect indexing for the smooth conv)
        for (int i = tid; i < RAWSZ; i += 256) {
            int wy = (int)(((unsigned)i * 11917u) >> 20);
            int wx = i - wy * RAWW;
            int R = r - 26 + wy;  R = R < 0 ? -R : (R > 127 ? 254 - R : R);
            int C = c0 - 26 + wx; C = C < 0 ? -C : (C > 127 ? 254 - C : C);
            raw[i] = __hip_atomic_load((float*)&src[R * S + C],
                                       __ATOMIC_RELAXED, __HIP_MEMORY_SCOPE_AGENT);
        }
        __syncthreads();
        // smooth 5x5 into win (perm layout), zero outside sheet
        for (int qi = tid; qi < 1029; qi += 256) {
            int wy  = (int)(((unsigned)qi * 49933u) >> 20);
            int wc0 = (qi - wy * 21) << 2;
            float acc[4] = {0.f, 0.f, 0.f, 0.f};
            #pragma unroll
            for (int a = 0; a < 5; a++) {
                const float* rp = &raw[(wy + a) * RAWW + wc0];
                v4f r0 = *(const v4f*)rp;
                v4f r1 = *(const v4f*)(rp + 4);
                float rv[8] = { r0[0], r0[1], r0[2], r0[3], r1[0], r1[1], r1[2], r1[3] };
                #pragma unroll
                for (int b = 0; b < 5; b++) {
                    float s = sreR[a * 5 + b];
                    #pragma unroll
                    for (int o = 0; o < 4; o++) acc[o] = fmaf(s, rv[b + o], acc[o]);
                }
            }
            int Rw = r - 24 + wy;
            bool rowok = (Rw >= 0) && (Rw < S);
            int pcol = wy * 21 + (wc0 >> 2);
            #pragma unroll
            for (int o = 0; o < 4; o++) {
                int C = c0 - 24 + wc0 + o;
                win[o * PROW + pcol] = (rowok && C >= 0 && C < S) ? acc[o] : 0.0f;
            }
        }
        __syncthreads();
        // per-unit dots from registers
        #pragma unroll
        for (int u = 0; u < 8; u++) {
            const int colofs = (wave << 3) + u;
            float acc = 0.0f;
            #pragma unroll
            for (int i = 0; i < 10; i++) {
                int a0 = boff[i] + colofs;
                int col0 = a0 >> 2;
                int rr = a0 & 3;
                #pragma unroll
                for (int e = 0; e < 4; e++) {
                    int ro = rr + e;
                    acc = fmaf((float)W[u][i][e],
                               win[(ro & 3) * PROW + col0 + (ro >> 2)], acc);
                }
            }
            #pragma unroll
            for (int off = 32; off > 0; off >>= 1) acc += __shfl_down(acc, off);
            if (lane == 0) {
                int ac = 2040 + colofs;  // 24*84 + 24 + colofs
                float ls = win[(ac & 3) * PROW + (ac >> 2)];
                float ln = fmaxf(ls + aff_r[u] - (2.5f / MSCALE) * acc, 0.0f) * 2.2f;
                ln = tanhf(ln * 1.5f) * (1.0f / 1.5f);
                lm_r[u] = 0.5f * lm_r[u] + 0.5f * ln;
                const int unit = r * S + c0 + colofs;
                __hip_atomic_store(&bufs[it & 1][unit], ln,
                                   __ATOMIC_RELAXED, __HIP_MEMORY_SCOPE_AGENT);
                if (it == 9) out_lat[unit] = ln;
            }
        }
        gbar(ctr, it);
    }

    // ---- Phase C: Hebbian correlation ----
    if (lane == 0) {
        #pragma unroll
        for (int u = 0; u < 8; u++) {
            const int unit = r * S + c0 + (wave << 3) + u;
            __hip_atomic_store(&lmb[unit], lm_r[u],
                               __ATOMIC_RELAXED, __HIP_MEMORY_SCOPE_AGENT);
        }
    }
    gbar(ctr, 10);
    for (int i = tid; i < 4116; i += 256) {
        int wy = (int)(((unsigned)i * 12484u) >> 20);
        int wc = i - wy * WINW;
        int R = r - 24 + wy, C = c0 - 24 + wc;
        float v = 0.0f;
        if (R >= 0 && R < S && C >= 0 && C < S)
            v = __hip_atomic_load(&lmb[R * S + C],
                                  __ATOMIC_RELAXED, __HIP_MEMORY_SCOPE_AGENT);
        win[(i & 3) * PROW + (i >> 2)] = v;
    }
    __syncthreads();
    float part = 0.0f;
    #pragma unroll
    for (int u = 0; u < 8; u++) {
        const int colofs = (wave << 3) + u;
        float acc = 0.0f;
        #pragma unroll
        for (int i = 0; i < 10; i++) {
            int a0 = boff[i] + colofs;
            int col0 = a0 >> 2;
            int rr = a0 & 3;
            #pragma unroll
            for (int e = 0; e < 4; e++) {
                int ro = rr + e;
                acc = fmaf((float)W[u][i][e],
                           win[(ro & 3) * PROW + col0 + (ro >> 2)], acc);
            }
        }
        #pragma unroll
        for (int off = 32; off > 0; off >>= 1) acc += __shfl_down(acc, off);
        if (lane == 0) part += lm_r[u] * (240.1f / MSCALE) * acc;
    }
    if (lane == 0) bred[wave] = part;
    __syncthreads();
    if (tid == 0) atomicAdd(out_corr, (bred[0] + bred[1]) + (bred[2] + bred[3]));
}

extern "C" void kernel_launch(void* const* d_in, const int* in_sizes, int n_in,
                              void* d_out, int out_size, void* d_ws, size_t ws_size,
                              hipStream_t stream) {
    const float* x        = (const float*)d_in[0];
    const float* rfs      = (const float*)d_in[1];
    const float* lw       = (const float*)d_in[2];
    const float* ada      = (const float*)d_in[3];
    const float* last_lat = (const float*)d_in[4];
    const float* lm0      = (const float*)d_in[5];
    float* out = (float*)d_out;
    float* ws  = (float*)d_ws;

    init_consts<<<1, 256, 0, stream>>>(ws);
    aff_kernel<<<L / 4, 256, 0, stream>>>(x, rfs, ada, ws + WS_AENVD,
                                          out, out + OUT_XT, ws + WS_AFF);
    fused_kernel<<<NBLK, 256, 0, stream>>>(lw, ws + WS_LRIJ, ws + WS_SRE,
                                           ws + WS_AFF, last_lat, lm0,
                                           ws + WS_BUF0, ws + WS_BUF1,
                                           ws + WS_LMB, (unsigned*)(ws + WS_CTR),
                                           out + OUT_LAT, out + OUT_CORR);
}